// Round 11
// baseline (897.788 us; speedup 1.0000x reference)
//
#include <hip/hip_runtime.h>
#include <hip/hip_bf16.h>
#include <math.h>

#define BB 32
#define NN 128
#define DD 1024
#define INF64 1e30

// ---------------- cost kernel: cost[b][i][j] = ||pred[b,i]-tgt[b,j]||_2 (f64) ----------------
// Norm decomposition (numpy form): sqrt(max(|a|^2+|b|^2-2 a.b, 0)), f64 accum.
// 64 threads/block, 8 A-rows staged as f64 in LDS, 2 B-cols/thread, XCD-swizzled.
__global__ __launch_bounds__(64) void cost_kernel(const float* __restrict__ pred,
                                                  const float* __restrict__ tgt,
                                                  double* __restrict__ cost) {
  extern __shared__ double a_s[];  // 8 * DD doubles = 64 KiB
  __shared__ double red_s[64];
  __shared__ double na_s[8];
  int s = blockIdx.x;
  int r8 = s & 7;
  int m = s >> 3;
  int t = m & 15;
  int q = m >> 4;
  int b = 8 * q + r8;
  int it = t << 3;                 // 8 rows of the cost matrix per block
  const float* Ab = pred + ((size_t)b * NN + it) * DD;
  const float* Bb = tgt + (size_t)b * NN * DD;
  const int lane = threadIdx.x;    // 0..63
  for (int tdx = lane; tdx < 8 * DD / 4; tdx += 64) {
    float4 v = ((const float4*)Ab)[tdx];
    double2* d = (double2*)&a_s[(size_t)tdx * 4];
    d[0] = double2{(double)v.x, (double)v.y};
    d[1] = double2{(double)v.z, (double)v.w};
  }
  __syncthreads();
  {
    int r = lane >> 3, o = lane & 7;
    const double* ar = a_s + (size_t)r * DD;
    double sum = 0.0;
    for (int k = o; k < DD; k += 8) { double x = ar[k]; sum += x * x; }
    red_s[lane] = sum;
  }
  __syncthreads();
  if (lane < 8) {
    double sum = 0.0;
#pragma unroll
    for (int mm = 0; mm < 8; mm++) sum += red_s[lane * 8 + mm];
    na_s[lane] = sum;
  }
  __syncthreads();
  const float4* brow0 = (const float4*)(Bb + (size_t)lane * DD);
  const float4* brow1 = (const float4*)(Bb + (size_t)(lane + 64) * DD);
  double acc0[8], acc1[8];
#pragma unroll
  for (int r = 0; r < 8; r++) { acc0[r] = 0.0; acc1[r] = 0.0; }
  double nb0 = 0.0, nb1 = 0.0;
  for (int k4 = 0; k4 < DD / 4; k4++) {
    float4 b0 = brow0[k4];
    float4 b1 = brow1[k4];
    double d00 = (double)b0.x, d01 = (double)b0.y, d02 = (double)b0.z, d03 = (double)b0.w;
    double d10 = (double)b1.x, d11 = (double)b1.y, d12 = (double)b1.z, d13 = (double)b1.w;
    nb0 += d00 * d00 + d01 * d01 + d02 * d02 + d03 * d03;
    nb1 += d10 * d10 + d11 * d11 + d12 * d12 + d13 * d13;
#pragma unroll
    for (int r = 0; r < 8; r++) {
      const double2* ap = (const double2*)(a_s + (size_t)r * DD + (size_t)k4 * 4);
      double2 x = ap[0];
      double2 y = ap[1];
      acc0[r] += x.x * d00 + x.y * d01 + y.x * d02 + y.y * d03;
      acc1[r] += x.x * d10 + x.y * d11 + y.x * d12 + y.y * d13;
    }
  }
#pragma unroll
  for (int r = 0; r < 8; r++) {
    double sq0 = na_s[r] + nb0 - 2.0 * acc0[r];
    double sq1 = na_s[r] + nb1 - 2.0 * acc1[r];
    size_t base = (((size_t)b * NN) + it + r) * NN;
    cost[base + lane] = sqrt(fmax(sq0, 0.0));
    cost[base + lane + 64] = sqrt(fmax(sq1, 0.0));
  }
}

// ---------------- cross-lane helpers (wave64, all lanes active) ----------------
union f64u { double d; unsigned int i[2]; };

__device__ __forceinline__ double readlane_f64(double x, int lane) {
  f64u u; u.d = x;
  f64u v;
  v.i[0] = (unsigned)__builtin_amdgcn_readlane((int)u.i[0], lane);
  v.i[1] = (unsigned)__builtin_amdgcn_readlane((int)u.i[1], lane);
  return v.d;
}

__device__ __forceinline__ double readpair_f64(double a, double b, int idx) {
  int l = (idx - 1) & 63;
  double ra = readlane_f64(a, l);
  double rb = readlane_f64(b, l);
  return ((idx - 1) >> 6) ? rb : ra;
}

__device__ __forceinline__ int readpair_i32(int a, int b, int idx) {
  int l = (idx - 1) & 63;
  int ra = __builtin_amdgcn_readlane(a, l);
  int rb = __builtin_amdgcn_readlane(b, l);
  return ((idx - 1) >> 6) ? rb : ra;
}

// pack nonnegative f64 value + 7-bit index into one sortable f64 key
__device__ __forceinline__ double pack_key(double m, int idx) {
  unsigned long long bits = __double_as_longlong(fmax(m, 0.0));
  bits = (bits & ~127ull) | (unsigned long long)idx;
  return __longlong_as_double(bits);
}

#define DPP_MIN_STEP(r, CTRL)                                                        \
  do {                                                                               \
    f64u _t; _t.d = (r);                                                             \
    f64u _s;                                                                         \
    _s.i[0] = (unsigned)__builtin_amdgcn_update_dpp((int)_t.i[0], (int)_t.i[0],      \
                                                    (CTRL), 0xF, 0xF, false);        \
    _s.i[1] = (unsigned)__builtin_amdgcn_update_dpp((int)_t.i[1], (int)_t.i[1],      \
                                                    (CTRL), 0xF, 0xF, false);        \
    (r) = fmin((r), _s.d);                                                           \
  } while (0)

#define DPP_MIN_CHAIN(r)          \
  do {                            \
    DPP_MIN_STEP(r, 0x111);       \
    DPP_MIN_STEP(r, 0x112);       \
    DPP_MIN_STEP(r, 0x114);       \
    DPP_MIN_STEP(r, 0x118);       \
    DPP_MIN_STEP(r, 0x142);       \
    DPP_MIN_STEP(r, 0x143);       \
  } while (0)

// u32 DPP min step (half the latency of the f64 step)
#define DPP_MINU_STEP(y, CTRL)                                                       \
  do {                                                                               \
    unsigned _s = (unsigned)__builtin_amdgcn_update_dpp((int)(y), (int)(y),          \
                                                        (CTRL), 0xF, 0xF, false);    \
    (y) = ((y) < _s) ? (y) : _s;                                                     \
  } while (0)

#define DPP_MINU_CHAIN(y)         \
  do {                            \
    DPP_MINU_STEP(y, 0x111);      \
    DPP_MINU_STEP(y, 0x112);      \
    DPP_MINU_STEP(y, 0x114);      \
    DPP_MINU_STEP(y, 0x118);      \
    DPP_MINU_STEP(y, 0x142);      \
    DPP_MINU_STEP(y, 0x143);      \
  } while (0)

// ---------------- Hungarian: colred + greedy + free-row reduction + exact SAP ----------------
// One batch per block, one wave; cost matrix in LDS (flat, conflict-free);
// all state register-resident (R9 structure — measured optimum; all
// pipelining/prefetch variants regressed). Scan argmin fast path: u32 DPP
// min over the upper-32 bits of the clamped per-lane min (nonnegative f64
// ordering == u64 bit ordering, coarsened); unique upper-32 winner provably
// holds the exact f64 min -> readlane index + exact value. Cross-lane
// upper-32 ties (rare) fall back to the exact packed-key f64 chain.
// Epilogue: node-loss contributions C[p[j],j]^2 written per column.
__global__ __launch_bounds__(64) void hungarian_kernel(const double* __restrict__ cost,
                                                       int* __restrict__ colfor,
                                                       double* __restrict__ nodeC) {
  extern __shared__ double lds[];   // [NN][NN] doubles = 128 KiB
  const int b = blockIdx.x;
  const double* C = cost + (size_t)b * NN * NN;
  const int lane = threadIdx.x;     // 0..63
  const int jA = lane + 1;          // 1-based columns owned by this lane
  const int jB = lane + 65;

  // preload full cost matrix to LDS
  {
    const double2* src = (const double2*)C;
    double2* dst = (double2*)lds;
#pragma unroll 8
    for (int t = lane; t < NN * NN / 2; t += 64) dst[t] = src[t];
  }
  __syncthreads();

  // ---- column reduction: v[j] = min_i C[i][j], arg = its row ----
  double vA = INF64, vB = INF64;
  int argA = 0, argB = 0;
#pragma unroll 4
  for (int i = 0; i < NN; i++) {
    double cA = lds[(size_t)i * NN + lane];
    double cB = lds[(size_t)i * NN + lane + 64];
    if (cA < vA) { vA = cA; argA = i + 1; }
    if (cB < vB) { vB = cB; argB = i + 1; }
  }

  // ---- greedy tight matching: columns ascending, assign argmin row if free ----
  unsigned long long asgLo = 0ull, asgHi = 0ull;   // matched rows
  int pA = 0, pB = 0;               // p for cols jA, jB (matched row, 0 = free)
  for (int j = 1; j <= NN; j++) {
    int ar = readpair_i32(argA, argB, j);
    bool freeRow = (ar <= 64) ? !((asgLo >> (ar - 1)) & 1ull)
                              : !((asgHi >> (ar - 65)) & 1ull);
    if (freeRow) {
      if (ar <= 64) asgLo |= 1ull << (ar - 1); else asgHi |= 1ull << (ar - 65);
      if (j == jA) pA = ar;
      if (j == jB) pB = ar;
    }
  }

  double uA = 0.0, uB = 0.0;        // u for rows lane+1, lane+65

  // ---- free-row reduction: u[i] = row-min reduced cost; match if argmin col free ----
  {
    unsigned long long fLo = __ballot(pA == 0);    // free-column masks
    unsigned long long fHi = __ballot(pB == 0);
    unsigned long long itLo = ~asgLo, itHi = ~asgHi;  // free rows
    while ((itLo | itHi) != 0ull) {
      int i = itLo ? (__builtin_ctzll(itLo) + 1) : (__builtin_ctzll(itHi) + 65);
      if (i <= 64) itLo &= ~(1ull << (i - 1)); else itHi &= ~(1ull << (i - 65));
      const double* crow = lds + (size_t)(i - 1) * NN;
      double candA = crow[lane] - vA;              // >= 0 (v = col min)
      double candB = crow[lane + 64] - vB;
      double r = fmin(pack_key(candA, lane), pack_key(candB, lane + 64));
      DPP_MIN_CHAIN(r);
      unsigned long long bits = __double_as_longlong(readlane_f64(r, 63));
      int jstar = (int)(bits & 127ull) + 1;
      double mi = readpair_f64(candA, candB, jstar);   // exact row-min slack
      if (i <= 64) { if (lane == i - 1) uA = mi; }
      else         { if (lane == i - 65) uB = mi; }
      bool jfree = (jstar <= 64) ? ((fLo >> (jstar - 1)) & 1ull)
                                 : ((fHi >> (jstar - 65)) & 1ull);
      if (jfree) {                                  // tight arc to a free col: match
        if (jstar == jA) pA = i;
        if (jstar == jB) pB = i;
        if (jstar <= 64) fLo &= ~(1ull << (jstar - 1));
        else             fHi &= ~(1ull << (jstar - 65));
        if (i <= 64) asgLo |= 1ull << (i - 1); else asgHi |= 1ull << (i - 65);
      }
    }
  }

  // ---- exact Dijkstra-SAP for rows still unassigned ----
  for (int i = 1; i <= NN; i++) {
    bool seeded = (i <= 64) ? ((asgLo >> (i - 1)) & 1ull)
                            : ((asgHi >> (i - 65)) & 1ull);
    if (seeded) continue;

    double minvA = INF64, minvB = INF64;
    int wayA = 0, wayB = 0;
    int usedA = 0, usedB = 0;
    unsigned long long usedRowLo = 0ull, usedRowHi = 0ull;
    int j0 = 0;
    int i0 = i;
    int jfin;
    while (true) {
      usedA |= (j0 == jA);
      usedB |= (j0 == jB);
      if (i0 <= 64) usedRowLo |= 1ull << (i0 - 1); else usedRowHi |= 1ull << (i0 - 65);
      double u_i0 = readpair_f64(uA, uB, i0);
      const double* crow = lds + (size_t)(i0 - 1) * NN;
      double cA = crow[lane];
      double cB = crow[lane + 64];
      double candA = cA - u_i0 - vA;
      double candB = cB - u_i0 - vB;
      if (!usedA && candA < minvA) { minvA = candA; wayA = j0; }
      if (!usedB && candB < minvB) { minvB = candB; wayB = j0; }
      // ---- argmin over free columns: u32 upper-half fast path ----
      double mAc = fmax(usedA ? INF64 : minvA, 0.0);
      double mBc = fmax(usedB ? INF64 : minvB, 0.0);
      bool selA = (mAc <= mBc);                 // tie -> A (smaller column)
      double mloc = selA ? mAc : mBc;
      int locIdx = selA ? jA : jB;
      f64u mu; mu.d = mloc;
      unsigned y = mu.i[1];                     // upper 32 bits (sign=0)
      unsigned yr = y;
      DPP_MINU_CHAIN(yr);
      unsigned ymin = (unsigned)__builtin_amdgcn_readlane((int)yr, 63);
      unsigned long long hit = __ballot(y == ymin);
      int j1; double delta;
      if (__builtin_popcountll(hit) == 1) {     // unique upper-32 winner: exact
        int Ls = __builtin_ctzll(hit);
        j1 = readpair_i32(locIdx, locIdx, Ls + 1);  // readlane(locIdx, Ls)
        delta = readlane_f64(mloc, Ls);
      } else {                                  // rare tie: exact packed-key chain
        double r = fmin(pack_key(mAc, lane), pack_key(mBc, lane + 64));
        DPP_MIN_CHAIN(r);
        unsigned long long bits = __double_as_longlong(readlane_f64(r, 63));
        j1 = (int)(bits & 127ull) + 1;
        delta = __longlong_as_double((long long)(bits & ~127ull));
      }
      // dual updates: u[tree rows] += delta; v[used cols] -= delta; minv[free] -= delta
      if ((usedRowLo >> lane) & 1ull) uA += delta;
      if ((usedRowHi >> lane) & 1ull) uB += delta;
      if (usedA) vA -= delta; else minvA -= delta;
      if (usedB) vB -= delta; else minvB -= delta;
      int pj1 = readpair_i32(pA, pB, j1);
      j0 = j1;
      if (pj1 == 0) { jfin = j1; break; }
      i0 = pj1;
    }
    int j = jfin;
    while (j) {
      int wj = readpair_i32(wayA, wayB, j);
      int pn = (wj == 0) ? i : readpair_i32(pA, pB, wj);
      if (j == jA) pA = pn;
      if (j == jB) pB = pn;
      j = wj;
    }
  }
  colfor[b * NN + (pA - 1)] = jA - 1;
  colfor[b * NN + (pB - 1)] = jB - 1;
  // node-loss contributions: C[p[j], j]^2 (dist^2 == sum of squared diffs)
  {
    double c1 = lds[(size_t)(pA - 1) * NN + lane];
    double c2 = lds[(size_t)(pB - 1) * NN + lane + 64];
    nodeC[b * NN + lane] = c1 * c1;
    nodeC[b * NN + lane + 64] = c2 * c2;
  }
}

// ---------------- edge loss: sum (pred_adj - tgt_adj[col,col])^2 ----------------
__global__ __launch_bounds__(256) void edge_loss_kernel(const float* __restrict__ padj,
                                                        const float* __restrict__ tadj,
                                                        const int* __restrict__ col,
                                                        double* __restrict__ partial) {
  const size_t total = (size_t)BB * NN * NN;
  double s = 0.0;
  for (size_t idx = (size_t)blockIdx.x * blockDim.x + threadIdx.x; idx < total;
       idx += (size_t)gridDim.x * blockDim.x) {
    int j = (int)(idx & (NN - 1));
    size_t bi = idx >> 7;
    int i = (int)(bi & (NN - 1));
    int b = (int)(bi >> 7);
    int ci = col[b * NN + i];
    int cj = col[b * NN + j];
    float diff = padj[idx] - tadj[((size_t)b * NN + ci) * NN + cj];
    s += (double)diff * (double)diff;
  }
  __shared__ double red[256];
  red[threadIdx.x] = s;
  __syncthreads();
  for (int off = 128; off > 0; off >>= 1) {
    if (threadIdx.x < off) red[threadIdx.x] += red[threadIdx.x + off];
    __syncthreads();
  }
  if (threadIdx.x == 0) partial[blockIdx.x] = red[0];
}

// ---------------- finalize: deterministic sum of partials -> d_out[2] ----------------
__global__ __launch_bounds__(256) void finalize_kernel(const double* __restrict__ nodeP, int nNode,
                                                       const double* __restrict__ edgeP, int nEdge,
                                                       float* __restrict__ out) {
  __shared__ double red[256];
  double s = 0.0;
  for (int t = threadIdx.x; t < nNode; t += 256) s += nodeP[t];
  red[threadIdx.x] = s;
  __syncthreads();
  for (int off = 128; off > 0; off >>= 1) {
    if (threadIdx.x < off) red[threadIdx.x] += red[threadIdx.x + off];
    __syncthreads();
  }
  double nodeSum = red[0];
  __syncthreads();
  s = 0.0;
  for (int t = threadIdx.x; t < nEdge; t += 256) s += edgeP[t];
  red[threadIdx.x] = s;
  __syncthreads();
  for (int off = 128; off > 0; off >>= 1) {
    if (threadIdx.x < off) red[threadIdx.x] += red[threadIdx.x + off];
    __syncthreads();
  }
  if (threadIdx.x == 0) {
    out[0] = (float)(nodeSum / (double)(NN * DD));
    out[1] = (float)(red[0] / (double)(NN * NN));
  }
}

extern "C" void kernel_launch(void* const* d_in, const int* in_sizes, int n_in,
                              void* d_out, int out_size, void* d_ws, size_t ws_size,
                              hipStream_t stream) {
  const float* pred_nodes   = (const float*)d_in[0];
  const float* target_nodes = (const float*)d_in[1];
  const float* pred_adj     = (const float*)d_in[2];
  const float* target_adj   = (const float*)d_in[3];
  float* out = (float*)d_out;

  char* ws = (char*)d_ws;
  double* cost = (double*)ws;                                   // 4 MiB
  size_t off = (size_t)BB * NN * NN * sizeof(double);
  int* col = (int*)(ws + off);                                  // 16 KiB
  off += (size_t)BB * NN * sizeof(int);
  double* nodeC = (double*)(ws + off);                          // 4096 doubles (32 KiB)
  off += (size_t)BB * NN * sizeof(double);
  double* edgeP = (double*)(ws + off);                          // 128 doubles

  cost_kernel<<<BB * 16, 64, 65536, stream>>>(pred_nodes, target_nodes, cost);
  hungarian_kernel<<<BB, 64, 131072, stream>>>(cost, col, nodeC);
  edge_loss_kernel<<<128, 256, 0, stream>>>(pred_adj, target_adj, col, edgeP);
  finalize_kernel<<<1, 256, 0, stream>>>(nodeC, BB * NN, edgeP, 128, out);
}

// Round 12
// 792.951 us; speedup vs baseline: 1.1322x; 1.1322x over previous
//
#include <hip/hip_runtime.h>
#include <hip/hip_bf16.h>
#include <math.h>

#define BB 32
#define NN 128
#define DD 1024
#define INF64 1e30

// ---------------- cost kernel: cost[b][i][j] = ||pred[b,i]-tgt[b,j]||_2 (f64) ----------------
// Norm decomposition (numpy form): sqrt(max(|a|^2+|b|^2-2 a.b, 0)), f64 accum.
// 64 threads/block, 8 A-rows staged as f64 in LDS, 2 B-cols/thread, XCD-swizzled.
__global__ __launch_bounds__(64) void cost_kernel(const float* __restrict__ pred,
                                                  const float* __restrict__ tgt,
                                                  double* __restrict__ cost) {
  extern __shared__ double a_s[];  // 8 * DD doubles = 64 KiB
  __shared__ double red_s[64];
  __shared__ double na_s[8];
  int s = blockIdx.x;
  int r8 = s & 7;
  int m = s >> 3;
  int t = m & 15;
  int q = m >> 4;
  int b = 8 * q + r8;
  int it = t << 3;                 // 8 rows of the cost matrix per block
  const float* Ab = pred + ((size_t)b * NN + it) * DD;
  const float* Bb = tgt + (size_t)b * NN * DD;
  const int lane = threadIdx.x;    // 0..63
  for (int tdx = lane; tdx < 8 * DD / 4; tdx += 64) {
    float4 v = ((const float4*)Ab)[tdx];
    double2* d = (double2*)&a_s[(size_t)tdx * 4];
    d[0] = double2{(double)v.x, (double)v.y};
    d[1] = double2{(double)v.z, (double)v.w};
  }
  __syncthreads();
  {
    int r = lane >> 3, o = lane & 7;
    const double* ar = a_s + (size_t)r * DD;
    double sum = 0.0;
    for (int k = o; k < DD; k += 8) { double x = ar[k]; sum += x * x; }
    red_s[lane] = sum;
  }
  __syncthreads();
  if (lane < 8) {
    double sum = 0.0;
#pragma unroll
    for (int mm = 0; mm < 8; mm++) sum += red_s[lane * 8 + mm];
    na_s[lane] = sum;
  }
  __syncthreads();
  const float4* brow0 = (const float4*)(Bb + (size_t)lane * DD);
  const float4* brow1 = (const float4*)(Bb + (size_t)(lane + 64) * DD);
  double acc0[8], acc1[8];
#pragma unroll
  for (int r = 0; r < 8; r++) { acc0[r] = 0.0; acc1[r] = 0.0; }
  double nb0 = 0.0, nb1 = 0.0;
  for (int k4 = 0; k4 < DD / 4; k4++) {
    float4 b0 = brow0[k4];
    float4 b1 = brow1[k4];
    double d00 = (double)b0.x, d01 = (double)b0.y, d02 = (double)b0.z, d03 = (double)b0.w;
    double d10 = (double)b1.x, d11 = (double)b1.y, d12 = (double)b1.z, d13 = (double)b1.w;
    nb0 += d00 * d00 + d01 * d01 + d02 * d02 + d03 * d03;
    nb1 += d10 * d10 + d11 * d11 + d12 * d12 + d13 * d13;
#pragma unroll
    for (int r = 0; r < 8; r++) {
      const double2* ap = (const double2*)(a_s + (size_t)r * DD + (size_t)k4 * 4);
      double2 x = ap[0];
      double2 y = ap[1];
      acc0[r] += x.x * d00 + x.y * d01 + y.x * d02 + y.y * d03;
      acc1[r] += x.x * d10 + x.y * d11 + y.x * d12 + y.y * d13;
    }
  }
#pragma unroll
  for (int r = 0; r < 8; r++) {
    double sq0 = na_s[r] + nb0 - 2.0 * acc0[r];
    double sq1 = na_s[r] + nb1 - 2.0 * acc1[r];
    size_t base = (((size_t)b * NN) + it + r) * NN;
    cost[base + lane] = sqrt(fmax(sq0, 0.0));
    cost[base + lane + 64] = sqrt(fmax(sq1, 0.0));
  }
}

// ---------------- cross-lane helpers (wave64, all lanes active) ----------------
union f64u { double d; unsigned int i[2]; };

__device__ __forceinline__ double readlane_f64(double x, int lane) {
  f64u u; u.d = x;
  f64u v;
  v.i[0] = (unsigned)__builtin_amdgcn_readlane((int)u.i[0], lane);
  v.i[1] = (unsigned)__builtin_amdgcn_readlane((int)u.i[1], lane);
  return v.d;
}

__device__ __forceinline__ double readpair_f64(double a, double b, int idx) {
  int l = (idx - 1) & 63;
  double ra = readlane_f64(a, l);
  double rb = readlane_f64(b, l);
  return ((idx - 1) >> 6) ? rb : ra;
}

__device__ __forceinline__ int readpair_i32(int a, int b, int idx) {
  int l = (idx - 1) & 63;
  int ra = __builtin_amdgcn_readlane(a, l);
  int rb = __builtin_amdgcn_readlane(b, l);
  return ((idx - 1) >> 6) ? rb : ra;
}

// pack nonnegative f64 value + 7-bit index into one sortable f64 key
__device__ __forceinline__ double pack_key(double m, int idx) {
  unsigned long long bits = __double_as_longlong(fmax(m, 0.0));
  bits = (bits & ~127ull) | (unsigned long long)idx;
  return __longlong_as_double(bits);
}

#define DPP_MIN_STEP(r, CTRL)                                                        \
  do {                                                                               \
    f64u _t; _t.d = (r);                                                             \
    f64u _s;                                                                         \
    _s.i[0] = (unsigned)__builtin_amdgcn_update_dpp((int)_t.i[0], (int)_t.i[0],      \
                                                    (CTRL), 0xF, 0xF, false);        \
    _s.i[1] = (unsigned)__builtin_amdgcn_update_dpp((int)_t.i[1], (int)_t.i[1],      \
                                                    (CTRL), 0xF, 0xF, false);        \
    (r) = fmin((r), _s.d);                                                           \
  } while (0)

#define DPP_MIN_CHAIN(r)          \
  do {                            \
    DPP_MIN_STEP(r, 0x111);       \
    DPP_MIN_STEP(r, 0x112);       \
    DPP_MIN_STEP(r, 0x114);       \
    DPP_MIN_STEP(r, 0x118);       \
    DPP_MIN_STEP(r, 0x142);       \
    DPP_MIN_STEP(r, 0x143);       \
  } while (0)

// ---------------- Hungarian: colred + greedy + free-row reduction + exact SAP ----------------
// One batch per block, one wave; cost matrix in LDS (flat, conflict-free);
// all state register-resident. This is the measured-optimal R9 structure:
// plain SAP scan body (no prefetch/pipelining/u32 paths — all 6 variants
// regressed), packed-key f64 DPP argmin, free-row reduction u-seed.
// Epilogue: node-loss contributions C[p[j],j]^2 written per column.
__global__ __launch_bounds__(64) void hungarian_kernel(const double* __restrict__ cost,
                                                       int* __restrict__ colfor,
                                                       double* __restrict__ nodeC) {
  extern __shared__ double lds[];   // [NN][NN] doubles = 128 KiB
  const int b = blockIdx.x;
  const double* C = cost + (size_t)b * NN * NN;
  const int lane = threadIdx.x;     // 0..63
  const int jA = lane + 1;          // 1-based columns owned by this lane
  const int jB = lane + 65;

  // preload full cost matrix to LDS
  {
    const double2* src = (const double2*)C;
    double2* dst = (double2*)lds;
#pragma unroll 8
    for (int t = lane; t < NN * NN / 2; t += 64) dst[t] = src[t];
  }
  __syncthreads();

  // ---- column reduction: v[j] = min_i C[i][j], arg = its row ----
  double vA = INF64, vB = INF64;
  int argA = 0, argB = 0;
#pragma unroll 4
  for (int i = 0; i < NN; i++) {
    double cA = lds[(size_t)i * NN + lane];
    double cB = lds[(size_t)i * NN + lane + 64];
    if (cA < vA) { vA = cA; argA = i + 1; }
    if (cB < vB) { vB = cB; argB = i + 1; }
  }

  // ---- greedy tight matching: columns ascending, assign argmin row if free ----
  unsigned long long asgLo = 0ull, asgHi = 0ull;   // matched rows
  int pA = 0, pB = 0;               // p for cols jA, jB (matched row, 0 = free)
  for (int j = 1; j <= NN; j++) {
    int ar = readpair_i32(argA, argB, j);
    bool freeRow = (ar <= 64) ? !((asgLo >> (ar - 1)) & 1ull)
                              : !((asgHi >> (ar - 65)) & 1ull);
    if (freeRow) {
      if (ar <= 64) asgLo |= 1ull << (ar - 1); else asgHi |= 1ull << (ar - 65);
      if (j == jA) pA = ar;
      if (j == jB) pB = ar;
    }
  }

  double uA = 0.0, uB = 0.0;        // u for rows lane+1, lane+65

  // ---- free-row reduction: u[i] = row-min reduced cost; match if argmin col free ----
  {
    unsigned long long fLo = __ballot(pA == 0);    // free-column masks
    unsigned long long fHi = __ballot(pB == 0);
    unsigned long long itLo = ~asgLo, itHi = ~asgHi;  // free rows
    while ((itLo | itHi) != 0ull) {
      int i = itLo ? (__builtin_ctzll(itLo) + 1) : (__builtin_ctzll(itHi) + 65);
      if (i <= 64) itLo &= ~(1ull << (i - 1)); else itHi &= ~(1ull << (i - 65));
      const double* crow = lds + (size_t)(i - 1) * NN;
      double candA = crow[lane] - vA;              // >= 0 (v = col min)
      double candB = crow[lane + 64] - vB;
      double r = fmin(pack_key(candA, lane), pack_key(candB, lane + 64));
      DPP_MIN_CHAIN(r);
      unsigned long long bits = __double_as_longlong(readlane_f64(r, 63));
      int jstar = (int)(bits & 127ull) + 1;
      double mi = readpair_f64(candA, candB, jstar);   // exact row-min slack
      if (i <= 64) { if (lane == i - 1) uA = mi; }
      else         { if (lane == i - 65) uB = mi; }
      bool jfree = (jstar <= 64) ? ((fLo >> (jstar - 1)) & 1ull)
                                 : ((fHi >> (jstar - 65)) & 1ull);
      if (jfree) {                                  // tight arc to a free col: match
        if (jstar == jA) pA = i;
        if (jstar == jB) pB = i;
        if (jstar <= 64) fLo &= ~(1ull << (jstar - 1));
        else             fHi &= ~(1ull << (jstar - 65));
        if (i <= 64) asgLo |= 1ull << (i - 1); else asgHi |= 1ull << (i - 65);
      }
    }
  }

  // ---- exact Dijkstra-SAP for rows still unassigned ----
  for (int i = 1; i <= NN; i++) {
    bool seeded = (i <= 64) ? ((asgLo >> (i - 1)) & 1ull)
                            : ((asgHi >> (i - 65)) & 1ull);
    if (seeded) continue;

    double minvA = INF64, minvB = INF64;
    int wayA = 0, wayB = 0;
    int usedA = 0, usedB = 0;
    unsigned long long usedRowLo = 0ull, usedRowHi = 0ull;
    int j0 = 0;
    int i0 = i;
    int jfin;
    while (true) {
      usedA |= (j0 == jA);
      usedB |= (j0 == jB);
      if (i0 <= 64) usedRowLo |= 1ull << (i0 - 1); else usedRowHi |= 1ull << (i0 - 65);
      double u_i0 = readpair_f64(uA, uB, i0);
      const double* crow = lds + (size_t)(i0 - 1) * NN;
      double cA = crow[lane];
      double cB = crow[lane + 64];
      double candA = cA - u_i0 - vA;
      double candB = cB - u_i0 - vB;
      if (!usedA && candA < minvA) { minvA = candA; wayA = j0; }
      if (!usedB && candB < minvB) { minvB = candB; wayB = j0; }
      double kA = pack_key(usedA ? INF64 : minvA, lane);
      double kB = pack_key(usedB ? INF64 : minvB, lane + 64);
      double r = fmin(kA, kB);
      DPP_MIN_CHAIN(r);
      double rmin = readlane_f64(r, 63);
      unsigned long long bits = __double_as_longlong(rmin);
      int j1 = (int)(bits & 127ull) + 1;
      double delta = __longlong_as_double((long long)(bits & ~127ull));
      if ((usedRowLo >> lane) & 1ull) uA += delta;
      if ((usedRowHi >> lane) & 1ull) uB += delta;
      if (usedA) vA -= delta; else minvA -= delta;
      if (usedB) vB -= delta; else minvB -= delta;
      int pj1 = readpair_i32(pA, pB, j1);
      j0 = j1;
      if (pj1 == 0) { jfin = j1; break; }
      i0 = pj1;
    }
    int j = jfin;
    while (j) {
      int wj = readpair_i32(wayA, wayB, j);
      int pn = (wj == 0) ? i : readpair_i32(pA, pB, wj);
      if (j == jA) pA = pn;
      if (j == jB) pB = pn;
      j = wj;
    }
  }
  colfor[b * NN + (pA - 1)] = jA - 1;
  colfor[b * NN + (pB - 1)] = jB - 1;
  // node-loss contributions: C[p[j], j]^2 (dist^2 == sum of squared diffs)
  {
    double c1 = lds[(size_t)(pA - 1) * NN + lane];
    double c2 = lds[(size_t)(pB - 1) * NN + lane + 64];
    nodeC[b * NN + lane] = c1 * c1;
    nodeC[b * NN + lane + 64] = c2 * c2;
  }
}

// ---------------- edge loss: sum (pred_adj - tgt_adj[col,col])^2 ----------------
__global__ __launch_bounds__(256) void edge_loss_kernel(const float* __restrict__ padj,
                                                        const float* __restrict__ tadj,
                                                        const int* __restrict__ col,
                                                        double* __restrict__ partial) {
  const size_t total = (size_t)BB * NN * NN;
  double s = 0.0;
  for (size_t idx = (size_t)blockIdx.x * blockDim.x + threadIdx.x; idx < total;
       idx += (size_t)gridDim.x * blockDim.x) {
    int j = (int)(idx & (NN - 1));
    size_t bi = idx >> 7;
    int i = (int)(bi & (NN - 1));
    int b = (int)(bi >> 7);
    int ci = col[b * NN + i];
    int cj = col[b * NN + j];
    float diff = padj[idx] - tadj[((size_t)b * NN + ci) * NN + cj];
    s += (double)diff * (double)diff;
  }
  __shared__ double red[256];
  red[threadIdx.x] = s;
  __syncthreads();
  for (int off = 128; off > 0; off >>= 1) {
    if (threadIdx.x < off) red[threadIdx.x] += red[threadIdx.x + off];
    __syncthreads();
  }
  if (threadIdx.x == 0) partial[blockIdx.x] = red[0];
}

// ---------------- finalize: deterministic sum of partials -> d_out[2] ----------------
__global__ __launch_bounds__(256) void finalize_kernel(const double* __restrict__ nodeP, int nNode,
                                                       const double* __restrict__ edgeP, int nEdge,
                                                       float* __restrict__ out) {
  __shared__ double red[256];
  double s = 0.0;
  for (int t = threadIdx.x; t < nNode; t += 256) s += nodeP[t];
  red[threadIdx.x] = s;
  __syncthreads();
  for (int off = 128; off > 0; off >>= 1) {
    if (threadIdx.x < off) red[threadIdx.x] += red[threadIdx.x + off];
    __syncthreads();
  }
  double nodeSum = red[0];
  __syncthreads();
  s = 0.0;
  for (int t = threadIdx.x; t < nEdge; t += 256) s += edgeP[t];
  red[threadIdx.x] = s;
  __syncthreads();
  for (int off = 128; off > 0; off >>= 1) {
    if (threadIdx.x < off) red[threadIdx.x] += red[threadIdx.x + off];
    __syncthreads();
  }
  if (threadIdx.x == 0) {
    out[0] = (float)(nodeSum / (double)(NN * DD));
    out[1] = (float)(red[0] / (double)(NN * NN));
  }
}

extern "C" void kernel_launch(void* const* d_in, const int* in_sizes, int n_in,
                              void* d_out, int out_size, void* d_ws, size_t ws_size,
                              hipStream_t stream) {
  const float* pred_nodes   = (const float*)d_in[0];
  const float* target_nodes = (const float*)d_in[1];
  const float* pred_adj     = (const float*)d_in[2];
  const float* target_adj   = (const float*)d_in[3];
  float* out = (float*)d_out;

  char* ws = (char*)d_ws;
  double* cost = (double*)ws;                                   // 4 MiB
  size_t off = (size_t)BB * NN * NN * sizeof(double);
  int* col = (int*)(ws + off);                                  // 16 KiB
  off += (size_t)BB * NN * sizeof(int);
  double* nodeC = (double*)(ws + off);                          // 4096 doubles (32 KiB)
  off += (size_t)BB * NN * sizeof(double);
  double* edgeP = (double*)(ws + off);                          // 128 doubles

  cost_kernel<<<BB * 16, 64, 65536, stream>>>(pred_nodes, target_nodes, cost);
  hungarian_kernel<<<BB, 64, 131072, stream>>>(cost, col, nodeC);
  edge_loss_kernel<<<128, 256, 0, stream>>>(pred_adj, target_adj, col, edgeP);
  finalize_kernel<<<1, 256, 0, stream>>>(nodeC, BB * NN, edgeP, 128, out);
}